// Round 3
// baseline (89.711 us; speedup 1.0000x reference)
//
#include <hip/hip_runtime.h>
#include <math.h>

#define BB 2
#define LL 2048
#define HH 128
#define NN 64
#define EPSF 1e-12f
#define T_A 13.8f       /* |z| > e^-13.8 = 1e-6  -> gate == 1 to <1e-6 */
#define T_C 34.5f       /* |z| < e^-34.5 = 1e-15 -> gate < ~1e-3, contribution negligible */
#define ROWP 66         /* LDS row pitch in floats: (2t+n)%32 bank spread */

__device__ __forceinline__ float bcast_lane(float v, int idx) {
  return __int_as_float(__builtin_amdgcn_readlane(__float_as_int(v), idx));
}

// Per-lane (h, n=lane) derived parameters. k = Cc * dB (C folded into state).
__device__ __forceinline__ void lane_params(
    const float* lar, const float* aim, const float* Bp, const float* ldt, const float* Cp,
    int h, int n,
    float& ar, float& ai, float& are, float& aie, float& kr, float& ki)
{
  float dt  = expf(ldt[0]);
  float lre = -expf(lar[h*NN + n]);   // Lam.re
  float w   = aim[h*NN + n];          // Lam.im
  ar = lre * dt;                      // dA.re
  ai = w   * dt;                      // dA.im
  float er = expf(ar);
  float s, c;
  sincosf(ai, &s, &c);
  are = er * c;  aie = er * s;        // a = exp(dA)
  float em1r = are - 1.0f, em1i = aie;
  float il2  = 1.0f / (lre*lre + w*w);
  float qr = (em1r*lre + em1i*w) * il2;   // (e^dA - 1)/Lam
  float qi = (em1i*lre - em1r*w) * il2;
  float br = Bp[(h*NN+n)*2+0], bi = Bp[(h*NN+n)*2+1];
  float dbr = br*qr - bi*qi, dbi = br*qi + bi*qr;
  float cr = Cp[n*2+0], ci = Cp[n*2+1];
  kr = cr*dbr - ci*dbi;
  ki = cr*dbi + ci*dbr;
}

// Uniform regime split points from wave min/max of decay rate.
__device__ __forceinline__ void regime_limits(float ar, int& tA_lim, int& tC_lim) {
  float arn = -ar;
  float mx = arn, mn = arn;
  #pragma unroll
  for (int m = 32; m >= 1; m >>= 1) {
    mx = fmaxf(mx, __shfl_xor(mx, m));
    mn = fminf(mn, __shfl_xor(mn, m));
  }
  tA_lim = (int)(T_A / mx);        // t <= tA_lim : all lanes gate==1
  tC_lim = (int)(T_C / mn) + 1;    // t >= tC_lim : all lanes input negligible
}

// ---------------- k1: per-chunk local end states ----------------
template<int LCH>
__global__ __launch_bounds__(256, 4)
void s4d_k1(const float* __restrict__ u, const float* __restrict__ lar,
            const float* __restrict__ aim, const float* __restrict__ Bp,
            const float* __restrict__ ldt, const float* __restrict__ Cp,
            float2* __restrict__ states)
{
  constexpr int NCHT = LL / LCH;
  int lane = threadIdx.x & 63;
  int wid  = blockIdx.x * 4 + (threadIdx.x >> 6);
  int c = wid % NCHT;
  int h = (wid / NCHT) & (HH-1);
  int b = wid / (NCHT * HH);

  float ar, ai, are, aie, kr, ki;
  lane_params(lar, aim, Bp, ldt, Cp, h, lane, ar, ai, are, aie, kr, ki);
  int tA_lim, tC_lim;
  regime_limits(ar, tA_lim, tC_lim);

  int t0 = c * LCH, t1 = t0 + LCH;
  size_t sidx = (((size_t)b*HH + h)*NCHT + c)*NN + lane;

  if (t0 >= tC_lim) { states[sidx] = make_float2(0.f, 0.f); return; }

  int e1 = min(t1, max(t0, tA_lim + 1));
  int e2 = min(t1, max(e1, tC_lim));

  const float* ub = u + (size_t)b * LL * HH + h;
  float ureg = ub[(size_t)min(t0 + lane, LL-1) * HH];
  float pr = 0.f, pi = 0.f;

  #pragma unroll 4
  for (int t = t0; t < e1; ++t) {            // regime A: gate == 1
    float uv = bcast_lane(ureg, t - t0);
    float prn = fmaf(are, pr, fmaf(-aie, pi, uv * kr));
    float pin = fmaf(aie, pr, fmaf( are, pi, uv * ki));
    pr = prn; pi = pin;
  }
  if (e2 > e1) {                             // regime B: full gate
    float rho = expf(ar * (float)e1);
    float th  = ai * (float)e1;
    float s, cth; sincosf(th, &s, &cth);
    float zr = rho * cth, zi = rho * s;
    for (int t = e1; t < e2; ++t) {
      float uv  = bcast_lane(ureg, t - t0);
      float dr  = zr + EPSF;
      float den = fmaf(dr, dr, zi*zi);
      float inv = 1.0f / den;
      float gr  = fmaf(zr, dr, zi*zi) * inv;
      float gi  = (zi*dr - zr*zi) * inv;
      float kgr = kr*gr - ki*gi, kgi = kr*gi + ki*gr;
      float prn = fmaf(are, pr, fmaf(-aie, pi, uv * kgr));
      float pin = fmaf(aie, pr, fmaf( are, pi, uv * kgi));
      pr = prn; pi = pin;
      float zrn = zr*are - zi*aie, zin = zr*aie + zi*are;
      zr = zrn; zi = zin;
    }
  }
  int dC = t1 - e2;                          // regime C: input == 0, pure decay
  if (dC > 0) {
    float rr = expf(ar * (float)dC);
    float s, cth; sincosf(ai * (float)dC, &s, &cth);
    float wr2 = rr * cth, wi2 = rr * s;
    float prn = pr*wr2 - pi*wi2;
    float pin = pr*wi2 + pi*wr2;
    pr = prn; pi = pin;
  }
  states[sidx] = make_float2(pr, pi);
}

// ---------------- k2: exclusive scan of chunk carries ----------------
template<int LCH>
__global__ __launch_bounds__(256)
void s4d_k2(const float* __restrict__ lar, const float* __restrict__ aim,
            const float* __restrict__ ldt, float2* __restrict__ states)
{
  constexpr int NCHT = LL / LCH;
  int tid = blockIdx.x * 256 + threadIdx.x;   // (b,h,n)
  int n = tid & 63;
  int h = (tid >> 6) & (HH-1);
  int b = tid >> 13;
  float dt  = expf(ldt[0]);
  float lre = -expf(lar[h*NN+n]);
  float ar  = lre*dt, ai = aim[h*NN+n]*dt;
  float rr  = expf(ar * (float)LCH);
  float s, c; sincosf(ai * (float)LCH, &s, &c);
  float Ar = rr*c, Ai = rr*s;                 // exp(dA*LCH)
  float xr = 0.f, xi = 0.f;
  size_t base = ((size_t)b*HH + h)*NCHT*NN + n;
  #pragma unroll 8
  for (int cc = 0; cc < NCHT; ++cc) {
    size_t idx = base + (size_t)cc*NN;
    float2 tmp = states[idx];
    states[idx] = make_float2(xr, xi);        // exclusive carry, in-place
    float xrn = fmaf(Ar, xr, fmaf(-Ai, xi, tmp.x));
    float xin = fmaf(Ai, xr, fmaf( Ar, xi, tmp.y));
    xr = xrn; xi = xin;
  }
}

// ---------------- k3: full scan from carries + y reduction ----------------
template<int LCH, int WPB>
__global__ __launch_bounds__(WPB*64, 2)
void s4d_k3(const float* __restrict__ u, const float* __restrict__ lar,
            const float* __restrict__ aim, const float* __restrict__ Bp,
            const float* __restrict__ ldt, const float* __restrict__ Cp,
            const float* __restrict__ Dp,
            const float2* __restrict__ states, float* __restrict__ out)
{
  constexpr int NCHT = LL / LCH;
  __shared__ float lds[WPB * LCH * ROWP];
  int lane = threadIdx.x & 63;
  int wv   = threadIdx.x >> 6;
  int wid  = blockIdx.x * WPB + wv;
  int c = wid % NCHT;
  int h = (wid / NCHT) & (HH-1);
  int b = wid / (NCHT * HH);
  float* myl = lds + wv * (LCH * ROWP);

  float ar, ai, are, aie, kr, ki;
  lane_params(lar, aim, Bp, ldt, Cp, h, lane, ar, ai, are, aie, kr, ki);
  int tA_lim, tC_lim;
  regime_limits(ar, tA_lim, tC_lim);

  int t0 = c * LCH, t1 = t0 + LCH;
  const float* ub = u + (size_t)b * LL * HH + h;
  float ureg = ub[(size_t)min(t0 + lane, LL-1) * HH];
  float Dh = Dp[h];

  if (t0 >= tC_lim) {                        // dead tail: y ~ 0
    if (lane < LCH) out[(size_t)b*LL*HH + (size_t)(t0+lane)*HH + h] = ureg * Dh;
    return;
  }

  int e1 = min(t1, max(t0, tA_lim + 1));
  int e2 = min(t1, max(e1, tC_lim));

  float2 cin = states[(((size_t)b*HH + h)*NCHT + c)*NN + lane];
  float pr = cin.x, pi = cin.y;

  #pragma unroll 4
  for (int t = t0; t < e1; ++t) {            // regime A
    float uv = bcast_lane(ureg, t - t0);
    float prn = fmaf(are, pr, fmaf(-aie, pi, uv * kr));
    float pin = fmaf(aie, pr, fmaf( are, pi, uv * ki));
    pr = prn; pi = pin;
    myl[(t - t0) * ROWP + lane] = pr;
  }
  if (e2 > e1) {                             // regime B
    float rho = expf(ar * (float)e1);
    float th  = ai * (float)e1;
    float s, cth; sincosf(th, &s, &cth);
    float zr = rho * cth, zi = rho * s;
    for (int t = e1; t < e2; ++t) {
      float uv  = bcast_lane(ureg, t - t0);
      float dr  = zr + EPSF;
      float den = fmaf(dr, dr, zi*zi);
      float inv = 1.0f / den;
      float gr  = fmaf(zr, dr, zi*zi) * inv;
      float gi  = (zi*dr - zr*zi) * inv;
      float kgr = kr*gr - ki*gi, kgi = kr*gi + ki*gr;
      float prn = fmaf(are, pr, fmaf(-aie, pi, uv * kgr));
      float pin = fmaf(aie, pr, fmaf( are, pi, uv * kgi));
      pr = prn; pi = pin;
      float zrn = zr*are - zi*aie, zin = zr*aie + zi*are;
      zr = zrn; zi = zin;
      myl[(t - t0) * ROWP + lane] = pr;
    }
  }
  #pragma unroll 4
  for (int t = e2; t < t1; ++t) {            // regime C: pure decay, still emit y
    float prn = fmaf(are, pr, -aie*pi);
    float pin = fmaf(aie, pr,  are*pi);
    pr = prn; pi = pin;
    myl[(t - t0) * ROWP + lane] = pr;
  }

  __builtin_amdgcn_s_waitcnt(0);             // lgkmcnt(0): own-wave LDS writes done

  if constexpr (LCH == 32) {
    // lane = m + 32*hf : lane m sums n in [hf*32, hf*32+32) of row m
    int m = lane & 31, hf = lane >> 5;
    const float* rowp = myl + m * ROWP + hf * 32;
    float s0 = 0.f, s1 = 0.f;
    #pragma unroll
    for (int j = 0; j < 16; ++j) {
      float2 v = *reinterpret_cast<const float2*>(rowp + 2*j);
      s0 += v.x; s1 += v.y;
    }
    float s = s0 + s1;
    s += __shfl_xor(s, 32);
    if (lane < 32)
      out[(size_t)b*LL*HH + (size_t)(t0+m)*HH + h] = s + ureg * Dh;
  } else {
    const float* rowp = myl + lane * ROWP;
    float s0 = 0.f, s1 = 0.f;
    #pragma unroll
    for (int j = 0; j < 32; ++j) {
      float2 v = *reinterpret_cast<const float2*>(rowp + 2*j);
      s0 += v.x; s1 += v.y;
    }
    out[(size_t)b*LL*HH + (size_t)(t0+lane)*HH + h] = (s0 + s1) + ureg * Dh;
  }
}

extern "C" void kernel_launch(void* const* d_in, const int* in_sizes, int n_in,
                              void* d_out, int out_size, void* d_ws, size_t ws_size,
                              hipStream_t stream)
{
  const float* u   = (const float*)d_in[0];
  const float* lar = (const float*)d_in[1];
  const float* aim = (const float*)d_in[2];
  const float* Bp  = (const float*)d_in[3];
  const float* ldt = (const float*)d_in[4];
  const float* Cp  = (const float*)d_in[5];
  const float* Dp  = (const float*)d_in[6];
  float* out = (float*)d_out;
  float2* states = (float2*)d_ws;

  size_t need32 = (size_t)BB*HH*(LL/32)*NN*sizeof(float2);   // 8 MB
  if (ws_size >= need32) {
    constexpr int LCH = 32, NCHT = LL/LCH;
    s4d_k1<LCH><<<dim3(BB*HH*NCHT/4), dim3(256), 0, stream>>>(u, lar, aim, Bp, ldt, Cp, states);
    s4d_k2<LCH><<<dim3(BB*HH*NN/256), dim3(256), 0, stream>>>(lar, aim, ldt, states);
    s4d_k3<LCH,4><<<dim3(BB*HH*NCHT/4), dim3(256), 0, stream>>>(u, lar, aim, Bp, ldt, Cp, Dp, states, out);
  } else {
    constexpr int LCH = 64, NCHT = LL/LCH;
    s4d_k1<LCH><<<dim3(BB*HH*NCHT/4), dim3(256), 0, stream>>>(u, lar, aim, Bp, ldt, Cp, states);
    s4d_k2<LCH><<<dim3(BB*HH*NN/256), dim3(256), 0, stream>>>(lar, aim, ldt, states);
    s4d_k3<LCH,2><<<dim3(BB*HH*NCHT/2), dim3(128), 0, stream>>>(u, lar, aim, Bp, ldt, Cp, Dp, states, out);
  }
}